// Round 1
// baseline (864.980 us; speedup 1.0000x reference)
//
#include <hip/hip_runtime.h>
#include <stdint.h>

#define B_Q   1024
#define KROWS 262144
#define DDIM  64
#define TOPK  5
#define NC    64              // K-chunks
#define KC    (KROWS / NC)    // 4096 rows per chunk
#define BQ    64              // queries per block
#define SUBR  128             // rows per LDS subtile
#define NSUB  (KC / SUBR)     // 32

typedef unsigned long long u64;

// order-preserving float->uint map (monotonic: bigger float => bigger uint)
__device__ __forceinline__ uint32_t ord32(float f) {
    uint32_t u = __float_as_uint(f);
    return (u & 0x80000000u) ? ~u : (u | 0x80000000u);
}

// tp[] kept sorted descending; insert key if it beats the min. Static indices
// only (dynamic-indexed register arrays spill to scratch).
__device__ __forceinline__ void insert5(u64 (&tp)[5], u64 key) {
    if (key > tp[4]) {
        tp[4] = key;
        u64 a, b;
        a = tp[3]; b = tp[4]; tp[3] = a > b ? a : b; tp[4] = a > b ? b : a;
        a = tp[2]; b = tp[3]; tp[2] = a > b ? a : b; tp[3] = a > b ? b : a;
        a = tp[1]; b = tp[2]; tp[1] = a > b ? a : b; tp[2] = a > b ? b : a;
        a = tp[0]; b = tp[1]; tp[0] = a > b ? a : b; tp[1] = a > b ? b : a;
    }
}

// Phase 1: per (query-tile, K-chunk) block: fp32 sim + per-query chunk top-5.
// Thread map: tq = t&15 owns 4 queries, trr = t>>4 owns 8 rows per subtile.
// LDS layouts are swizzled per-thread-group with +1 float4 pad so compute
// ds_read_b128s are 2-way-conflict/broadcast only.
__global__ __launch_bounds__(256, 2) void p1(const float* __restrict__ Qg,
                                             const float* __restrict__ Mg,
                                             u64* __restrict__ wsK) {
    __shared__ float4 Qs[16 * 65];    // 16.25 KiB; reused as cand buffer at end
    __shared__ float4 Ms[16 * 129];   // 32.25 KiB

    const int t   = threadIdx.x;
    const int tq  = t & 15;
    const int trr = t >> 4;
    const int qbase = blockIdx.x * BQ;
    const int kbase = blockIdx.y * KC;

    // stage Q once: Qs[(q>>2)*65 + ds*4 + (q&3)]
    {
        const float4* Qg4 = (const float4*)(Qg + (size_t)qbase * DDIM);
        #pragma unroll
        for (int k = 0; k < 4; ++k) {
            int e  = t + 256 * k;          // 0..1023
            int qL = e >> 4, ds = e & 15;
            Qs[(qL >> 2) * 65 + ds * 4 + (qL & 3)] = Qg4[e];
        }
    }

    u64 top[4][5];
    #pragma unroll
    for (int i = 0; i < 4; ++i)
        #pragma unroll
        for (int s = 0; s < 5; ++s) top[i][s] = 0ull;

    for (int sb = 0; sb < NSUB; ++sb) {
        __syncthreads();
        // stage M subtile: Ms[(r>>3)*129 + ds*8 + (r&7)]
        const float4* Mg4 = (const float4*)(Mg + (size_t)(kbase + sb * SUBR) * DDIM);
        #pragma unroll
        for (int k = 0; k < 8; ++k) {
            int e  = t + 256 * k;          // 0..2047, coalesced global reads
            int rL = e >> 4, ds = e & 15;
            Ms[(rL >> 3) * 129 + ds * 8 + (rL & 7)] = Mg4[e];
        }
        __syncthreads();

        float acc[4][8];
        #pragma unroll
        for (int i = 0; i < 4; ++i)
            #pragma unroll
            for (int j = 0; j < 8; ++j) acc[i][j] = 0.f;

        #pragma unroll 4
        for (int ds = 0; ds < 16; ++ds) {
            float4 qf[4], mf[8];
            #pragma unroll
            for (int i = 0; i < 4; ++i) qf[i] = Qs[tq * 65 + ds * 4 + i];
            #pragma unroll
            for (int j = 0; j < 8; ++j) mf[j] = Ms[trr * 129 + ds * 8 + j];
            #pragma unroll
            for (int i = 0; i < 4; ++i)
                #pragma unroll
                for (int j = 0; j < 8; ++j) {
                    acc[i][j] = fmaf(qf[i].x, mf[j].x, acc[i][j]);
                    acc[i][j] = fmaf(qf[i].y, mf[j].y, acc[i][j]);
                    acc[i][j] = fmaf(qf[i].z, mf[j].z, acc[i][j]);
                    acc[i][j] = fmaf(qf[i].w, mf[j].w, acc[i][j]);
                }
        }

        // fold this subtile's 4x8 sims into per-thread top-5 lists.
        // key = ord(val)<<32 | ~idx  => max key = max val, ties -> lower idx
        const uint32_t rowb = (uint32_t)(kbase + sb * SUBR + trr * 8);
        #pragma unroll
        for (int j = 0; j < 8; ++j) {
            uint32_t nidx = ~(rowb + (uint32_t)j);
            #pragma unroll
            for (int i = 0; i < 4; ++i) {
                u64 key = ((u64)ord32(acc[i][j]) << 32) | (u64)nidx;
                insert5(top[i], key);
            }
        }
    }

    // in-wave butterfly merge across the 4 lanes sharing tq (lanes ^16, ^32).
    // Lockstep wave execution keeps stage boundaries consistent; snapshot
    // remote keys into r[] before mutating so no double-insert.
    #pragma unroll
    for (int i = 0; i < 4; ++i) {
        #pragma unroll
        for (int d = 16; d <= 32; d <<= 1) {
            u64 r[5];
            #pragma unroll
            for (int s = 0; s < 5; ++s) r[s] = __shfl_xor(top[i][s], d, 64);
            #pragma unroll
            for (int s = 0; s < 5; ++s) insert5(top[i], r[s]);
        }
    }

    __syncthreads();                 // everyone is done reading Qs
    u64* cand = (u64*)&Qs[0];        // 64 queries x 4 waves x 5 keys = 10 KiB
    if ((trr & 3) == 0) {
        const int w = trr >> 2;      // wave id
        #pragma unroll
        for (int i = 0; i < 4; ++i) {
            int q = tq * 4 + i;
            #pragma unroll
            for (int s = 0; s < 5; ++s) cand[(q * 4 + w) * 5 + s] = top[i][s];
        }
    }
    __syncthreads();
    if (t < 64) {
        u64 best[5] = {0ull, 0ull, 0ull, 0ull, 0ull};
        #pragma unroll
        for (int w = 0; w < 4; ++w)
            #pragma unroll
            for (int s = 0; s < 5; ++s) insert5(best, cand[(t * 4 + w) * 5 + s]);
        const int gq = qbase + t;
        size_t base = ((size_t)blockIdx.y * B_Q + (size_t)gq) * TOPK;
        #pragma unroll
        for (int s = 0; s < 5; ++s) wsK[base + s] = best[s];
    }
}

// Phase 2: one 64-lane wave per query. Merge 64 chunks x 5 candidates via
// wave-max, then gather the winning memory rows (coalesced 64-float rows).
__global__ __launch_bounds__(64) void p2(const float* __restrict__ Mg,
                                         const u64* __restrict__ wsK,
                                         float* __restrict__ out) {
    const int Q    = blockIdx.x;
    const int lane = threadIdx.x;

    u64 loc[5];
    #pragma unroll
    for (int m = 0; m < 5; ++m) {
        int flat = m * 64 + lane;            // 0..319 = 64 chunks * 5
        int c = flat / 5, j = flat - c * 5;
        loc[m] = wsK[((size_t)c * B_Q + (size_t)Q) * TOPK + j];
    }

    #pragma unroll
    for (int it = 0; it < TOPK; ++it) {
        u64 bk = loc[0];
        #pragma unroll
        for (int m = 1; m < 5; ++m) bk = loc[m] > bk ? loc[m] : bk;
        u64 wk = bk;
        #pragma unroll
        for (int off = 32; off >= 1; off >>= 1) {
            u64 o = __shfl_xor(wk, off, 64);
            wk = o > wk ? o : wk;
        }
        uint32_t idx = ~(uint32_t)(wk & 0xffffffffull);
        out[((size_t)Q * TOPK + it) * DDIM + lane] = Mg[(size_t)idx * DDIM + lane];
        // keys are globally unique -> exactly one copy gets retired
        #pragma unroll
        for (int m = 0; m < 5; ++m) if (loc[m] == wk) loc[m] = 0ull;
    }
}

extern "C" void kernel_launch(void* const* d_in, const int* in_sizes, int n_in,
                              void* d_out, int out_size, void* d_ws, size_t ws_size,
                              hipStream_t stream) {
    const float* Qg = (const float*)d_in[0];
    const float* Mg = (const float*)d_in[1];
    // d_in[2] = topk (always 5 per the reference; compile-time TOPK)
    float* out = (float*)d_out;
    u64* wsK = (u64*)d_ws;   // needs NC*B_Q*TOPK*8 = 2.62 MB

    dim3 g1(B_Q / BQ, NC);   // (16 query tiles, 64 K-chunks)
    p1<<<g1, 256, 0, stream>>>(Qg, Mg, wsK);
    p2<<<B_Q, 64, 0, stream>>>(Mg, wsK, out);
}

// Round 2
// 540.683 us; speedup vs baseline: 1.5998x; 1.5998x over previous
//
#include <hip/hip_runtime.h>
#include <stdint.h>

typedef unsigned long long u64;
typedef __attribute__((ext_vector_type(8))) short short8;   // 8 bf16 (4 VGPRs)
typedef __attribute__((ext_vector_type(4))) float f32x4;

#define KROWS  262144
#define DDIM   64
#define NQ     1024
#define NC     64                 // K-chunks
#define CHUNK  (KROWS / NC)       // 4096 rows
#define SUB    128                // rows per LDS subtile
#define NSUB   (CHUNK / SUB)      // 32
#define KC_PER 6                  // keys kept per (chunk, query)
// sentinel: key of -inf sim, so thrf stays a real float (never NaN)
#define KINIT  0x007FFFFF00000000ull

__device__ __forceinline__ uint32_t ord32(float f) {
    uint32_t u = __float_as_uint(f);
    return (u & 0x80000000u) ? ~u : (u | 0x80000000u);
}
__device__ __forceinline__ float inv_ord(uint32_t k) {
    return __uint_as_float((k & 0x80000000u) ? (k ^ 0x80000000u) : ~k);
}
template <int N>
__device__ __forceinline__ void insN(u64 (&tp)[N], u64 key) {
    // caller guarantees key > tp[N-1]
    tp[N - 1] = key;
    #pragma unroll
    for (int i = N - 1; i > 0; --i) {
        u64 a = tp[i - 1], b = tp[i];
        tp[i - 1] = a > b ? a : b;
        tp[i]     = a > b ? b : a;
    }
}
__device__ __forceinline__ uint32_t bf16rne(float f) {
    uint32_t u = __float_as_uint(f);
    return (u + 0x7fffu + ((u >> 16) & 1u)) >> 16;
}
__device__ __forceinline__ uint32_t pack2(float a, float b) {
    return bf16rne(a) | (bf16rne(b) << 16);
}
__device__ __forceinline__ void gload_lds16(const void* g, void* l) {
    __builtin_amdgcn_global_load_lds(
        (const __attribute__((address_space(1))) uint32_t*)g,
        (__attribute__((address_space(3))) uint32_t*)l, 16, 0, 0);
}

// Kernel 0: fp32 memory -> bf16 (row-major [KROWS][64]), RNE
__global__ __launch_bounds__(256) void conv(const float* __restrict__ Mf,
                                            uint16_t* __restrict__ Mb) {
    const int stride = gridDim.x * 256;
    const float4* src = (const float4*)Mf;
    uint4* dst = (uint4*)Mb;
    for (int e = blockIdx.x * 256 + threadIdx.x; e < (KROWS * DDIM / 8); e += stride) {
        const float4 a = src[2 * e], b = src[2 * e + 1];
        uint4 o;
        o.x = pack2(a.x, a.y); o.y = pack2(a.z, a.w);
        o.z = pack2(b.x, b.y); o.w = pack2(b.z, b.w);
        dst[e] = o;
    }
}

// Kernel 1: bf16 MFMA prefilter. Block = 512 thr (8 waves), grid (4 qcols, NC).
// Wave owns 32 queries (2 MFMA qtiles); block scans its 4096-row chunk.
// LDS M-subtile uses XOR swizzle: 16B chunk (row, c) holds global chunk
// c ^ (row&7) of that row, matching global_load_lds's lane-linear dest and
// making compute ds_read_b128s 2-way max (free).
__global__ __launch_bounds__(512, 2) void p1(const float* __restrict__ Qg,
                                             const uint16_t* __restrict__ Mb,
                                             u64* __restrict__ wsK) {
    __shared__ __align__(16) unsigned char smem[49152];  // 2x16KB stage, then cand
    uint16_t* stage = (uint16_t*)smem;
    const int t = threadIdx.x;
    const int lane = t & 63;
    const int w = t >> 6;
    const int quad = lane >> 4;
    const int m = lane & 15;
    const int qcol = blockIdx.x;
    const int chunk = blockIdx.y;
    const int qBase = qcol * 256 + w * 32;
    const int rowChunk = chunk * CHUNK;

    // A-frags: A[m=lane&15][k=quad*8+j], fp32->bf16 inline. [qt][khalf]
    short8 afr[2][2];
    #pragma unroll
    for (int qt = 0; qt < 2; ++qt)
        #pragma unroll
        for (int kh = 0; kh < 2; ++kh) {
            const float* qp = Qg + (size_t)(qBase + qt * 16 + m) * DDIM + quad * 8 + kh * 32;
            const float4 f0 = ((const float4*)qp)[0];
            const float4 f1 = ((const float4*)qp)[1];
            short8 a;
            a[0] = (short)bf16rne(f0.x); a[1] = (short)bf16rne(f0.y);
            a[2] = (short)bf16rne(f0.z); a[3] = (short)bf16rne(f0.w);
            a[4] = (short)bf16rne(f1.x); a[5] = (short)bf16rne(f1.y);
            a[6] = (short)bf16rne(f1.z); a[7] = (short)bf16rne(f1.w);
            afr[qt][kh] = a;
        }

    u64 top[8][6];      // 8 lists: qt*4+reg, per-lane (query, row mod 16 class)
    float thrf[8];
    #pragma unroll
    for (int li = 0; li < 8; ++li) {
        thrf[li] = -3.4e38f;
        #pragma unroll
        for (int s = 0; s < 6; ++s) top[li][s] = KINIT;
    }

    auto stage_sub = [&](int sb, int buf) {
        const uint16_t* src = Mb + (size_t)(rowChunk + sb * SUB) * DDIM;
        #pragma unroll
        for (int i = 0; i < 2; ++i) {
            const int slotBase = w * 128 + i * 64;
            const int slot = slotBase + lane;
            const int row = slot >> 3, c = slot & 7;
            const int g = row * 8 + (c ^ (row & 7));   // swizzled source chunk
            gload_lds16(src + (size_t)g * 8, stage + buf * 8192 + slotBase * 8);
        }
    };

    stage_sub(0, 0);
    for (int sb = 0; sb < NSUB; ++sb) {
        __syncthreads();   // stage(sb) drained (vmcnt0) + compute(sb-1) done
        if (sb + 1 < NSUB) stage_sub(sb + 1, (sb + 1) & 1);
        const uint16_t* bufp = stage + (sb & 1) * 8192;
        #pragma unroll 2
        for (int rt = 0; rt < 8; ++rt) {
            const int r = rt * 16 + m;   // this lane's row-in-subtile (B col n)
            const short8 b0 = *(const short8*)(bufp + r * 64 + ((quad       ^ (r & 7)) * 8));
            const short8 b1 = *(const short8*)(bufp + r * 64 + (((quad + 4) ^ (r & 7)) * 8));
            f32x4 c0 = {0.f, 0.f, 0.f, 0.f}, c1 = {0.f, 0.f, 0.f, 0.f};
            c0 = __builtin_amdgcn_mfma_f32_16x16x32_bf16(afr[0][0], b0, c0, 0, 0, 0);
            c0 = __builtin_amdgcn_mfma_f32_16x16x32_bf16(afr[0][1], b1, c0, 0, 0, 0);
            c1 = __builtin_amdgcn_mfma_f32_16x16x32_bf16(afr[1][0], b0, c1, 0, 0, 0);
            c1 = __builtin_amdgcn_mfma_f32_16x16x32_bf16(afr[1][1], b1, c1, 0, 0, 0);
            const uint32_t rowG = (uint32_t)(rowChunk + sb * SUB) + (uint32_t)r;
            const u64 nidx = (u64)~rowG;
            #pragma unroll
            for (int reg = 0; reg < 4; ++reg) {
                const float s0 = c0[reg];
                if (s0 > thrf[reg]) {
                    insN<6>(top[reg], ((u64)ord32(s0) << 32) | nidx);
                    thrf[reg] = inv_ord((uint32_t)(top[reg][5] >> 32));
                }
                const float s1 = c1[reg];
                if (s1 > thrf[4 + reg]) {
                    insN<6>(top[4 + reg], ((u64)ord32(s1) << 32) | nidx);
                    thrf[4 + reg] = inv_ord((uint32_t)(top[4 + reg][5] >> 32));
                }
            }
        }
    }
    __syncthreads();   // all waves done with staging buffers

    // butterfly xor 1,2 within the quad: each 4-lane group merged (snapshot
    // remote before mutating — round-1 pattern; key sets are disjoint)
    #pragma unroll
    for (int d = 1; d <= 2; d <<= 1) {
        #pragma unroll
        for (int li = 0; li < 8; ++li) {
            u64 rm[6];
            #pragma unroll
            for (int s = 0; s < 6; ++s) rm[s] = __shfl_xor(top[li][s], d, 64);
            #pragma unroll
            for (int s = 0; s < 6; ++s)
                if (rm[s] > top[li][5]) insN<6>(top[li], rm[s]);
        }
    }

    u64* cand = (u64*)smem;   // 256 queries x 4 groups x 6 keys = 48 KiB
    if ((lane & 3) == 0) {
        const int slot = (lane >> 2) & 3;
        #pragma unroll
        for (int li = 0; li < 8; ++li) {
            const int ql = w * 32 + (li >> 2) * 16 + quad * 4 + (li & 3);
            #pragma unroll
            for (int s = 0; s < 6; ++s) cand[(ql * 4 + slot) * 6 + s] = top[li][s];
        }
    }
    __syncthreads();
    if (t < 256) {
        u64 best[6];
        #pragma unroll
        for (int s = 0; s < 6; ++s) best[s] = 0;
        for (int j = 0; j < 24; ++j) {
            const u64 k = cand[t * 24 + j];
            if (k > best[5]) insN<6>(best, k);
        }
        const size_t base = ((size_t)chunk * NQ + (size_t)(qcol * 256 + t)) * KC_PER;
        #pragma unroll
        for (int s = 0; s < 6; ++s) wsK[base + s] = best[s];
    }
}

// Kernel 2: per-query wave: merge 64 chunks x 6 keys -> bf16 top-16 ->
// exact fp32 rescore -> top-5 -> gather rows.
__global__ __launch_bounds__(64) void p2(const float* __restrict__ Qg,
                                         const float* __restrict__ Mf,
                                         const u64* __restrict__ wsK,
                                         float* __restrict__ out) {
    const int Q = blockIdx.x;
    const int lane = threadIdx.x;
    u64 loc[6];
    #pragma unroll
    for (int i = 0; i < 6; ++i) {
        const int flat = i * 64 + lane;          // 0..383
        const int c = flat / 6, s = flat - c * 6;
        loc[i] = wsK[((size_t)c * NQ + (size_t)Q) * KC_PER + s];
    }
    const float qv = Qg[(size_t)Q * DDIM + lane];
    u64 best[5] = {0, 0, 0, 0, 0};
    for (int it = 0; it < 16; ++it) {
        u64 wk = loc[0];
        #pragma unroll
        for (int i2 = 1; i2 < 6; ++i2) wk = loc[i2] > wk ? loc[i2] : wk;
        #pragma unroll
        for (int off = 32; off >= 1; off >>= 1) {
            const u64 o = __shfl_xor(wk, off, 64);
            wk = o > wk ? o : wk;
        }
        #pragma unroll
        for (int i2 = 0; i2 < 6; ++i2) if (loc[i2] == wk) loc[i2] = 0;  // unique keys
        const uint32_t idx = ~(uint32_t)wk;
        float p = qv * Mf[(size_t)idx * DDIM + lane];
        #pragma unroll
        for (int off = 32; off >= 1; off >>= 1) p += __shfl_xor(p, off, 64);
        const u64 rkey = ((u64)ord32(p) << 32) | (u64)(~idx);
        if (rkey > best[4]) insN<5>(best, rkey);   // uniform across lanes
    }
    #pragma unroll
    for (int j = 0; j < 5; ++j) {
        const uint32_t idx = ~(uint32_t)best[j];
        out[((size_t)Q * 5 + j) * DDIM + lane] = Mf[(size_t)idx * DDIM + lane];
    }
}

extern "C" void kernel_launch(void* const* d_in, const int* in_sizes, int n_in,
                              void* d_out, int out_size, void* d_ws, size_t ws_size,
                              hipStream_t stream) {
    const float* Qg = (const float*)d_in[0];
    const float* Mf = (const float*)d_in[1];
    float* out = (float*)d_out;
    u64* wsK = (u64*)d_ws;                                  // 64*1024*6*8 = 3 MB
    uint16_t* Mb = (uint16_t*)((char*)d_ws + (4u << 20));   // 33.5 MB bf16 bank

    conv<<<2048, 256, 0, stream>>>(Mf, Mb);
    p1<<<dim3(4, NC), 512, 0, stream>>>(Qg, Mb, wsK);
    p2<<<NQ, 64, 0, stream>>>(Qg, Mf, wsK, out);
}

// Round 3
// 224.404 us; speedup vs baseline: 3.8546x; 2.4094x over previous
//
#include <hip/hip_runtime.h>
#include <stdint.h>

typedef unsigned long long u64;
typedef __attribute__((ext_vector_type(8))) short short8;   // 8 bf16 (4 VGPRs)
typedef __attribute__((ext_vector_type(4))) float f32x4;

#define KROWS  262144
#define DDIM   64
#define NQ     1024
#define NC     64                 // K-chunks
#define CHUNK  (KROWS / NC)       // 4096 rows
#define SUB    128                // rows per LDS subtile
#define NSUB   (CHUNK / SUB)      // 32
#define KC_PER 6                  // keys kept per (chunk, query)

__device__ __forceinline__ uint32_t ord32(float f) {
    uint32_t u = __float_as_uint(f);
    return (u & 0x80000000u) ? ~u : (u | 0x80000000u);
}
// key = 24-bit monotone sim bits | 8-bit pos (pos wave-uniform at call site)
__device__ __forceinline__ uint32_t mkkey(float s, uint32_t posU) {
    uint32_t u = __float_as_uint(s);
    uint32_t sgn = (uint32_t)((int32_t)u >> 31) | 0x80000000u;
    return ((u ^ sgn) & 0xFFFFFF00u) | posU;
}
// med3 written as max(min(a,b), min(max(a,b), c)) so ISel can match v_med3_u32
__device__ __forceinline__ uint32_t med3u(uint32_t a, uint32_t b, uint32_t c) {
    uint32_t mn = a < b ? a : b;
    uint32_t mx = a > b ? a : b;
    uint32_t t  = mx < c ? mx : c;
    return mn > t ? mn : t;
}
// branchless sorted-desc top-5 insert: n_i = med3(t[i-1], t[i], k)
__device__ __forceinline__ void fold5(uint32_t (&t)[5], uint32_t k) {
    t[4] = med3u(t[3], t[4], k);
    t[3] = med3u(t[2], t[3], k);
    t[2] = med3u(t[1], t[2], k);
    t[1] = med3u(t[0], t[1], k);
    t[0] = t[0] > k ? t[0] : k;
}
template <int N>
__device__ __forceinline__ void insN(u64 (&tp)[N], u64 key) {
    // caller guarantees key > tp[N-1]; tp sorted desc
    tp[N - 1] = key;
    #pragma unroll
    for (int i = N - 1; i > 0; --i) {
        u64 a = tp[i - 1], b = tp[i];
        tp[i - 1] = a > b ? a : b;
        tp[i]     = a > b ? b : a;
    }
}
__device__ __forceinline__ void cs64(u64& a, u64& b) {
    u64 x = a, y = b;
    a = x > y ? x : y;
    b = x > y ? y : x;
}
__device__ __forceinline__ uint32_t bf16rne(float f) {
    uint32_t u = __float_as_uint(f);
    return (u + 0x7fffu + ((u >> 16) & 1u)) >> 16;
}
__device__ __forceinline__ uint32_t pack2(float a, float b) {
    return bf16rne(a) | (bf16rne(b) << 16);
}
__device__ __forceinline__ void gload_lds16(const void* g, void* l) {
    __builtin_amdgcn_global_load_lds(
        (const __attribute__((address_space(1))) uint32_t*)g,
        (__attribute__((address_space(3))) uint32_t*)l, 16, 0, 0);
}

// Kernel 0: fp32 memory -> bf16 (row-major [KROWS][64]), RNE
__global__ __launch_bounds__(256) void conv(const float* __restrict__ Mf,
                                            uint16_t* __restrict__ Mb) {
    const int stride = gridDim.x * 256;
    const float4* src = (const float4*)Mf;
    uint4* dst = (uint4*)Mb;
    for (int e = blockIdx.x * 256 + threadIdx.x; e < (KROWS * DDIM / 8); e += stride) {
        const float4 a = src[2 * e], b = src[2 * e + 1];
        uint4 o;
        o.x = pack2(a.x, a.y); o.y = pack2(a.z, a.w);
        o.z = pack2(b.x, b.y); o.w = pack2(b.z, b.w);
        dst[e] = o;
    }
}

// Kernel 1: bf16 MFMA prefilter with branchless u32 per-class top-5 fold.
// Block = 512 thr (8 waves), grid (4 qcols, NC). Wave owns 32 queries.
__global__ __launch_bounds__(512, 2) void p1(const float* __restrict__ Qg,
                                             const uint16_t* __restrict__ Mb,
                                             u64* __restrict__ wsK) {
    __shared__ __align__(16) unsigned char smem[49152];  // 2x16KB stage, then cand
    uint16_t* stage = (uint16_t*)smem;
    const int t = threadIdx.x;
    const int lane = t & 63;
    const int w = t >> 6;
    const int quad = lane >> 4;
    const int m = lane & 15;
    const int qcol = blockIdx.x;
    const int chunk = blockIdx.y;
    const int qBase = qcol * 256 + w * 32;
    const int rowChunk = chunk * CHUNK;

    // A-frags: A[m=lane&15][k=quad*8+j], fp32->bf16 inline. [qt][khalf]
    short8 afr[2][2];
    #pragma unroll
    for (int qt = 0; qt < 2; ++qt)
        #pragma unroll
        for (int kh = 0; kh < 2; ++kh) {
            const float* qp = Qg + (size_t)(qBase + qt * 16 + m) * DDIM + quad * 8 + kh * 32;
            const float4 f0 = ((const float4*)qp)[0];
            const float4 f1 = ((const float4*)qp)[1];
            short8 a;
            a[0] = (short)bf16rne(f0.x); a[1] = (short)bf16rne(f0.y);
            a[2] = (short)bf16rne(f0.z); a[3] = (short)bf16rne(f0.w);
            a[4] = (short)bf16rne(f1.x); a[5] = (short)bf16rne(f1.y);
            a[6] = (short)bf16rne(f1.z); a[7] = (short)bf16rne(f1.w);
            afr[qt][kh] = a;
        }

    // 8 lists (qt*4+reg), each top-5 u32 keys, class = m (row mod 16)
    uint32_t top[8][5];
    #pragma unroll
    for (int li = 0; li < 8; ++li)
        #pragma unroll
        for (int s = 0; s < 5; ++s) top[li][s] = 0u;

    auto stage_sub = [&](int sb, int buf) {
        const uint16_t* src = Mb + (size_t)(rowChunk + sb * SUB) * DDIM;
        #pragma unroll
        for (int i = 0; i < 2; ++i) {
            const int slotBase = w * 128 + i * 64;
            const int slot = slotBase + lane;
            const int row = slot >> 3, c = slot & 7;
            const int g = row * 8 + (c ^ (row & 7));   // swizzled source chunk
            gload_lds16(src + (size_t)g * 8, stage + buf * 8192 + slotBase * 8);
        }
    };

    stage_sub(0, 0);
    for (int sb = 0; sb < NSUB; ++sb) {
        __syncthreads();
        if (sb + 1 < NSUB) stage_sub(sb + 1, (sb + 1) & 1);
        const uint16_t* bufp = stage + (sb & 1) * 8192;
        #pragma unroll 2
        for (int rt = 0; rt < 8; ++rt) {
            const int r = rt * 16 + m;   // this lane's row-in-subtile (B col n)
            const short8 b0 = *(const short8*)(bufp + r * 64 + ((quad       ^ (r & 7)) * 8));
            const short8 b1 = *(const short8*)(bufp + r * 64 + (((quad + 4) ^ (r & 7)) * 8));
            f32x4 c0 = {0.f, 0.f, 0.f, 0.f}, c1 = {0.f, 0.f, 0.f, 0.f};
            c0 = __builtin_amdgcn_mfma_f32_16x16x32_bf16(afr[0][0], b0, c0, 0, 0, 0);
            c0 = __builtin_amdgcn_mfma_f32_16x16x32_bf16(afr[0][1], b1, c0, 0, 0, 0);
            c1 = __builtin_amdgcn_mfma_f32_16x16x32_bf16(afr[1][0], b0, c1, 0, 0, 0);
            c1 = __builtin_amdgcn_mfma_f32_16x16x32_bf16(afr[1][1], b1, c1, 0, 0, 0);
            const uint32_t posU = (uint32_t)(sb * 8 + rt);   // wave-uniform, 8 bits
            #pragma unroll
            for (int reg = 0; reg < 4; ++reg) {
                fold5(top[reg],     mkkey(c0[reg], posU));
                fold5(top[4 + reg], mkkey(c1[reg], posU));
            }
        }
    }
    __syncthreads();   // staging buffers dead; smem reusable

    // Expand u32 -> u64 keys, merge classes: xor 1,2 butterfly then LDS.
    // Full key: (simbits<<32) | ~rowG, rowG = rowChunk + pos*16 + m.
    u64* cand = (u64*)smem;   // 256 queries x 4 groups x 6 keys = 48 KiB
    const uint32_t rowBase = (uint32_t)rowChunk + (uint32_t)m;
    #pragma unroll
    for (int g = 0; g < 2; ++g) {       // qt groups serialized to cap VGPRs
        u64 tl[4][6];
        #pragma unroll
        for (int r4 = 0; r4 < 4; ++r4) {
            const int li = g * 4 + r4;
            #pragma unroll
            for (int s = 0; s < 5; ++s) {
                const uint32_t k = top[li][s];
                const uint32_t rowG = rowBase + (k & 255u) * 16u;
                tl[r4][s] = ((u64)(k & 0xFFFFFF00u) << 32) | (u64)(~rowG);
            }
            tl[r4][5] = 0ull;
            // re-sort desc (expansion can invert exact-tie order): insertion net
            cs64(tl[r4][0], tl[r4][1]);
            cs64(tl[r4][1], tl[r4][2]); cs64(tl[r4][0], tl[r4][1]);
            cs64(tl[r4][2], tl[r4][3]); cs64(tl[r4][1], tl[r4][2]); cs64(tl[r4][0], tl[r4][1]);
            cs64(tl[r4][3], tl[r4][4]); cs64(tl[r4][2], tl[r4][3]); cs64(tl[r4][1], tl[r4][2]); cs64(tl[r4][0], tl[r4][1]);
        }
        #pragma unroll
        for (int d = 1; d <= 2; d <<= 1) {
            #pragma unroll
            for (int r4 = 0; r4 < 4; ++r4) {
                u64 rm[6];
                #pragma unroll
                for (int s = 0; s < 6; ++s) rm[s] = __shfl_xor(tl[r4][s], d, 64);
                #pragma unroll
                for (int s = 0; s < 6; ++s)
                    if (rm[s] > tl[r4][5]) insN<6>(tl[r4], rm[s]);
            }
        }
        if ((lane & 3) == 0) {
            const int slot = (lane >> 2) & 3;   // surviving class group m>>2
            #pragma unroll
            for (int r4 = 0; r4 < 4; ++r4) {
                const int ql = w * 32 + g * 16 + quad * 4 + r4;
                #pragma unroll
                for (int s = 0; s < 6; ++s) cand[(ql * 4 + slot) * 6 + s] = tl[r4][s];
            }
        }
    }
    __syncthreads();
    if (t < 256) {
        u64 best[6] = {0, 0, 0, 0, 0, 0};
        for (int j = 0; j < 24; ++j) {
            const u64 k = cand[t * 24 + j];
            if (k > best[5]) insN<6>(best, k);
        }
        const size_t base = ((size_t)chunk * NQ + (size_t)(qcol * 256 + t)) * KC_PER;
        #pragma unroll
        for (int s = 0; s < 6; ++s) wsK[base + s] = best[s];
    }
}

// Kernel 2: per-query wave. Extract bf16-top-16 indices (shuffle-only), load
// all 16 rows in parallel, exact fp32 rescore, top-5, write from registers.
__global__ __launch_bounds__(64) void p2(const float* __restrict__ Qg,
                                         const float* __restrict__ Mf,
                                         const u64* __restrict__ wsK,
                                         float* __restrict__ out) {
    const int Q = blockIdx.x;
    const int lane = threadIdx.x;
    u64 loc[6];
    #pragma unroll
    for (int i = 0; i < 6; ++i) {
        const int flat = i * 64 + lane;          // 0..383 = 64 chunks x 6
        const int c = flat / 6, s = flat - c * 6;
        loc[i] = wsK[((size_t)c * NQ + (size_t)Q) * KC_PER + s];
    }
    uint32_t idxs[16];
    #pragma unroll
    for (int it = 0; it < 16; ++it) {
        u64 wk = loc[0];
        #pragma unroll
        for (int i2 = 1; i2 < 6; ++i2) wk = loc[i2] > wk ? loc[i2] : wk;
        #pragma unroll
        for (int off = 32; off >= 1; off >>= 1) {
            const u64 o = __shfl_xor(wk, off, 64);
            wk = o > wk ? o : wk;
        }
        #pragma unroll
        for (int i2 = 0; i2 < 6; ++i2) if (loc[i2] == wk) loc[i2] = 0;  // unique
        idxs[it] = ~(uint32_t)wk;                // wave-uniform row index
    }
    // 16 independent row loads (latency overlapped), fp32 rescore
    const float qv = Qg[(size_t)Q * DDIM + lane];
    float v[16];
    #pragma unroll
    for (int j = 0; j < 16; ++j) v[j] = Mf[(size_t)idxs[j] * DDIM + lane];
    u64 rk[16];
    #pragma unroll
    for (int j = 0; j < 16; ++j) {
        float p = qv * v[j];
        #pragma unroll
        for (int off = 32; off >= 1; off >>= 1) p += __shfl_xor(p, off, 64);
        rk[j] = ((u64)ord32(p) << 32) | (u64)(~idxs[j]);
    }
    #pragma unroll
    for (int it = 0; it < 5; ++it) {
        u64 best = rk[0];
        #pragma unroll
        for (int j = 1; j < 16; ++j) best = rk[j] > best ? rk[j] : best;
        float o = 0.f;
        #pragma unroll
        for (int j = 0; j < 16; ++j) o = (rk[j] == best) ? v[j] : o;  // keys unique
        out[((size_t)Q * 5 + it) * DDIM + lane] = o;
        #pragma unroll
        for (int j = 0; j < 16; ++j) rk[j] = (rk[j] == best) ? 0ull : rk[j];
    }
}

extern "C" void kernel_launch(void* const* d_in, const int* in_sizes, int n_in,
                              void* d_out, int out_size, void* d_ws, size_t ws_size,
                              hipStream_t stream) {
    const float* Qg = (const float*)d_in[0];
    const float* Mf = (const float*)d_in[1];
    float* out = (float*)d_out;
    u64* wsK = (u64*)d_ws;                                  // 64*1024*6*8 = 3 MB
    uint16_t* Mb = (uint16_t*)((char*)d_ws + (4u << 20));   // 33.5 MB bf16 bank

    conv<<<2048, 256, 0, stream>>>(Mf, Mb);
    p1<<<dim3(4, NC), 512, 0, stream>>>(Qg, Mb, wsK);
    p2<<<NQ, 64, 0, stream>>>(Qg, Mf, wsK, out);
}

// Round 4
// 190.840 us; speedup vs baseline: 4.5325x; 1.1759x over previous
//
#include <hip/hip_runtime.h>
#include <stdint.h>

typedef unsigned long long u64;
typedef __attribute__((ext_vector_type(8))) short short8;   // 8 bf16 (4 VGPRs)
typedef __attribute__((ext_vector_type(4))) float f32x4;

#define KROWS  262144
#define DDIM   64
#define NQ     1024
#define NC     128                // K-chunks
#define CHUNK  (KROWS / NC)       // 2048 rows
#define SUB    128                // rows per LDS subtile
#define NSUB   (CHUNK / SUB)      // 16
#define KSTRIDE 8                 // u32 slots per (chunk,query) in ws (5 used)
#define BIAS   128.0f             // acc bias => all sims positive => raw bits monotone
#define SIMMASK 0xFFFFF800u       // top 21 bits sim, low 11 bits row-in-chunk

__device__ __forceinline__ uint32_t ord32(float f) {
    uint32_t u = __float_as_uint(f);
    return (u & 0x80000000u) ? ~u : (u | 0x80000000u);
}
// guaranteed v_med3_u32 (LLVM's int-med3 combine needs an imm; force it)
__device__ __forceinline__ uint32_t med3u(uint32_t a, uint32_t b, uint32_t c) {
    uint32_t d;
    asm("v_med3_u32 %0, %1, %2, %3" : "=v"(d) : "v"(a), "v"(b), "v"(c));
    return d;
}
// branchless sorted-desc top-5 insert: 4 med3 + 1 max, all on OLD values
__device__ __forceinline__ void fold5(uint32_t (&t)[5], uint32_t k) {
    uint32_t n4 = med3u(t[3], t[4], k);
    uint32_t n3 = med3u(t[2], t[3], k);
    uint32_t n2 = med3u(t[1], t[2], k);
    uint32_t n1 = med3u(t[0], t[1], k);
    t[0] = t[0] > k ? t[0] : k;
    t[1] = n1; t[2] = n2; t[3] = n3; t[4] = n4;
}
__device__ __forceinline__ uint32_t bf16rne(float f) {
    uint32_t u = __float_as_uint(f);
    return (u + 0x7fffu + ((u >> 16) & 1u)) >> 16;
}
__device__ __forceinline__ uint32_t pack2(float a, float b) {
    return bf16rne(a) | (bf16rne(b) << 16);
}
__device__ __forceinline__ void gload_lds16(const void* g, void* l) {
    __builtin_amdgcn_global_load_lds(
        (const __attribute__((address_space(1))) uint32_t*)g,
        (__attribute__((address_space(3))) uint32_t*)l, 16, 0, 0);
}

// Kernel 0: fp32 memory -> bf16 (row-major [KROWS][64]), RNE
__global__ __launch_bounds__(256) void conv(const float* __restrict__ Mf,
                                            uint16_t* __restrict__ Mb) {
    const int stride = gridDim.x * 256;
    const float4* src = (const float4*)Mf;
    uint4* dst = (uint4*)Mb;
    for (int e = blockIdx.x * 256 + threadIdx.x; e < (KROWS * DDIM / 8); e += stride) {
        const float4 a = src[2 * e], b = src[2 * e + 1];
        uint4 o;
        o.x = pack2(a.x, a.y); o.y = pack2(a.z, a.w);
        o.z = pack2(b.x, b.y); o.w = pack2(b.z, b.w);
        dst[e] = o;
    }
}

// Kernel 1: bf16 MFMA prefilter, branchless med3 top-5 fold, u32 keys carrying
// (sim21 | row11). Block = 512 thr (8 waves), grid (4 qcols, 128 chunks),
// 2 blocks/CU. Wave owns 32 queries (2 MFMA qtiles).
__global__ __launch_bounds__(512, 4) void p1(const float* __restrict__ Qg,
                                             const uint16_t* __restrict__ Mb,
                                             uint32_t* __restrict__ wsK) {
    __shared__ __align__(16) uint16_t stage[2 * 8192];   // 2 x 16 KiB dbuf
    const int t = threadIdx.x;
    const int lane = t & 63;
    const int w = t >> 6;
    const int quad = lane >> 4;
    const int m = lane & 15;
    const int qcol = blockIdx.x;
    const int chunk = blockIdx.y;
    const int qBase = qcol * 256 + w * 32;
    const int rowChunk = chunk * CHUNK;

    // A-frags: A[m=lane&15][k=quad*8+j], fp32->bf16 inline. [qt][khalf]
    short8 afr[2][2];
    #pragma unroll
    for (int qt = 0; qt < 2; ++qt)
        #pragma unroll
        for (int kh = 0; kh < 2; ++kh) {
            const float* qp = Qg + (size_t)(qBase + qt * 16 + m) * DDIM + quad * 8 + kh * 32;
            const float4 f0 = ((const float4*)qp)[0];
            const float4 f1 = ((const float4*)qp)[1];
            short8 a;
            a[0] = (short)bf16rne(f0.x); a[1] = (short)bf16rne(f0.y);
            a[2] = (short)bf16rne(f0.z); a[3] = (short)bf16rne(f0.w);
            a[4] = (short)bf16rne(f1.x); a[5] = (short)bf16rne(f1.y);
            a[6] = (short)bf16rne(f1.z); a[7] = (short)bf16rne(f1.w);
            afr[qt][kh] = a;
        }
    const f32x4 bias = {BIAS, BIAS, BIAS, BIAS};

    // 8 lists (qt*4+reg = query class), top-5 u32 keys, row class = m
    uint32_t top[8][5];
    #pragma unroll
    for (int li = 0; li < 8; ++li)
        #pragma unroll
        for (int s = 0; s < 5; ++s) top[li][s] = 0u;

    auto stage_sub = [&](int sb, int buf) {
        const uint16_t* src = Mb + (size_t)(rowChunk + sb * SUB) * DDIM;
        #pragma unroll
        for (int i = 0; i < 2; ++i) {
            const int slotBase = w * 128 + i * 64;
            const int slot = slotBase + lane;
            const int row = slot >> 3, c = slot & 7;
            const int g = row * 8 + (c ^ (row & 7));   // swizzled source chunk
            gload_lds16(src + (size_t)g * 8, stage + buf * 8192 + slotBase * 8);
        }
    };

    stage_sub(0, 0);
    for (int sb = 0; sb < NSUB; ++sb) {
        __syncthreads();
        if (sb + 1 < NSUB) stage_sub(sb + 1, (sb + 1) & 1);
        const uint16_t* bufp = stage + (sb & 1) * 8192;
        const uint32_t pb = (uint32_t)m + (uint32_t)sb * 128u;   // row11 base
        #pragma unroll
        for (int rt = 0; rt < 8; ++rt) {
            const int r = rt * 16 + m;   // lane's row-in-subtile (B col n)
            // r&7 == m&7 (rt*16 = 0 mod 8): swizzle is rt-invariant, rt*2048B
            // folds into the ds_read immediate offset
            const short8 b0 = *(const short8*)(bufp + r * 64 + ((quad       ^ (m & 7)) * 8));
            const short8 b1 = *(const short8*)(bufp + r * 64 + (((quad + 4) ^ (m & 7)) * 8));
            f32x4 c0, c1;
            c0 = __builtin_amdgcn_mfma_f32_16x16x32_bf16(afr[0][0], b0, bias, 0, 0, 0);
            c0 = __builtin_amdgcn_mfma_f32_16x16x32_bf16(afr[0][1], b1, c0,   0, 0, 0);
            c1 = __builtin_amdgcn_mfma_f32_16x16x32_bf16(afr[1][0], b0, bias, 0, 0, 0);
            c1 = __builtin_amdgcn_mfma_f32_16x16x32_bf16(afr[1][1], b1, c1,   0, 0, 0);
            const uint32_t posm = pb + (uint32_t)(rt * 16);   // (pos<<4)|m
            #pragma unroll
            for (int reg = 0; reg < 4; ++reg) {
                // sims positive (bias): raw bits monotone; 1x v_and_or_b32
                fold5(top[reg],     (__float_as_uint(c0[reg]) & SIMMASK) | posm);
                fold5(top[4 + reg], (__float_as_uint(c1[reg]) & SIMMASK) | posm);
            }
        }
    }

    // full in-wave class merge: butterfly xor 1,2,4,8 across the 16 m-lanes.
    // Coverage sets are disjoint at every round -> no duplicates; keys carry
    // their row, so they stay self-describing across lanes.
    #pragma unroll
    for (int d = 1; d <= 8; d <<= 1) {
        #pragma unroll
        for (int li = 0; li < 8; ++li) {
            uint32_t rm[5];
            #pragma unroll
            for (int s = 0; s < 5; ++s) rm[s] = __shfl_xor(top[li][s], d, 64);
            #pragma unroll
            for (int s = 0; s < 5; ++s) fold5(top[li], rm[s]);
        }
    }

    if (m == 0) {   // 4 lanes/wave hold the merged lists for all 32 queries
        #pragma unroll
        for (int li = 0; li < 8; ++li) {
            const int q = qBase + (li >> 2) * 16 + quad * 4 + (li & 3);
            uint32_t* p = wsK + ((size_t)chunk * NQ + (size_t)q) * KSTRIDE;
            uint4 v4; v4.x = top[li][0]; v4.y = top[li][1];
            v4.z = top[li][2]; v4.w = top[li][3];
            *(uint4*)p = v4;
            p[4] = top[li][4];
        }
    }
}

// Kernel 2: per-query wave. Merge 128 chunks x 5 u32 keys -> top-16 by
// prefilter sim -> parallel row loads -> exact fp32 rescore -> top-5.
__global__ __launch_bounds__(64) void p2(const float* __restrict__ Qg,
                                         const float* __restrict__ Mf,
                                         const uint32_t* __restrict__ wsK,
                                         float* __restrict__ out) {
    const int Q = blockIdx.x;
    const int lane = threadIdx.x;
    u64 mk[10];
    #pragma unroll
    for (int i = 0; i < 10; ++i) {
        const int flat = i * 64 + lane;          // 0..639 = 128 chunks x 5
        const int c = flat / 5, s = flat - c * 5;
        const uint32_t k = wsK[((size_t)c * NQ + (size_t)Q) * KSTRIDE + s];
        const uint32_t grow = (uint32_t)c * (uint32_t)CHUNK + (k & 2047u);
        mk[i] = ((u64)k << 32) | (u64)grow;      // unique (grow unique)
    }
    uint32_t idxs[16];
    #pragma unroll
    for (int it = 0; it < 16; ++it) {
        u64 wk = mk[0];
        #pragma unroll
        for (int i2 = 1; i2 < 10; ++i2) wk = mk[i2] > wk ? mk[i2] : wk;
        #pragma unroll
        for (int off = 32; off >= 1; off >>= 1) {
            const u64 o = __shfl_xor(wk, off, 64);
            wk = o > wk ? o : wk;
        }
        #pragma unroll
        for (int i2 = 0; i2 < 10; ++i2) if (mk[i2] == wk) mk[i2] = 0;
        idxs[it] = (uint32_t)wk;                 // global row, wave-uniform
    }
    // 16 independent row loads (latency overlapped), exact fp32 rescore
    const float qv = Qg[(size_t)Q * DDIM + lane];
    float v[16];
    #pragma unroll
    for (int j = 0; j < 16; ++j) v[j] = Mf[(size_t)idxs[j] * DDIM + lane];
    u64 rk[16];
    #pragma unroll
    for (int j = 0; j < 16; ++j) {
        float p = qv * v[j];
        #pragma unroll
        for (int off = 32; off >= 1; off >>= 1) p += __shfl_xor(p, off, 64);
        rk[j] = ((u64)ord32(p) << 32) | (u64)(~idxs[j]);   // ties -> lower idx
    }
    #pragma unroll
    for (int it = 0; it < 5; ++it) {
        u64 best = rk[0];
        #pragma unroll
        for (int j = 1; j < 16; ++j) best = rk[j] > best ? rk[j] : best;
        float o = 0.f;
        #pragma unroll
        for (int j = 0; j < 16; ++j) o = (rk[j] == best) ? v[j] : o;  // unique
        out[((size_t)Q * 5 + it) * DDIM + lane] = o;
        #pragma unroll
        for (int j = 0; j < 16; ++j) rk[j] = (rk[j] == best) ? 0ull : rk[j];
    }
}

extern "C" void kernel_launch(void* const* d_in, const int* in_sizes, int n_in,
                              void* d_out, int out_size, void* d_ws, size_t ws_size,
                              hipStream_t stream) {
    const float* Qg = (const float*)d_in[0];
    const float* Mf = (const float*)d_in[1];
    float* out = (float*)d_out;
    uint32_t* wsK = (uint32_t*)d_ws;                        // 128*1024*8*4 = 4 MB
    uint16_t* Mb = (uint16_t*)((char*)d_ws + (4u << 20));   // 33.5 MB bf16 bank

    conv<<<2048, 256, 0, stream>>>(Mf, Mb);
    p1<<<dim3(4, NC), 512, 0, stream>>>(Qg, Mb, wsK);
    p2<<<NQ, 64, 0, stream>>>(Qg, Mf, wsK, out);
}